// Round 5
// baseline (477.562 us; speedup 1.0000x reference)
//
#include <hip/hip_runtime.h>

// GAT layer, N=8192, F_IN=256, F_OUT=128.
// K1 wh: Wh = h@W (fp32 VALU) + WhT (f16 transposed [c][j]).
// K2 f12: f1 = Wh@a1, f2 = Wh@a2.
// K3 attn: block = 16 rows x 2048-j quarter (JSPLIT=4) -> 2048 blocks, 4/CU
//   resident (launch_bounds(256,4), LDS 24.5 KB). Per iter: adj 16x128 tile
//   DMA'd to LDS (global_load_lds 16B, NT aux, rotation-swizzled rows),
//   B-frags + f2 via VGPR loads issued BEFORE the DMA (vmcnt-FIFO: their
//   waits leave the DMA in flight), scores->f16->MFMA 16x16x32, psum via
//   ones-MFMA. Double-buffered LDS, __syncthreads per iter; occupancy
//   (4 blocks/CU) decorrelates the barrier bubbles -> adj stream saturates.
// K4 comb: sum 4 j-partials, normalize.
// NOTE: dur_us includes ~240-260us of harness reset (1GB ws fill + adj
// restore) -- structural floor ~300us.

#define N_NODES 8192
#define F_IN 256
#define F_OUT 128
#define RPB 16                      // rows per block
#define JCH 128                     // j per chunk (per iteration)
#define JSPLIT 4
#define JRANGE (N_NODES / JSPLIT)   // 2048
#define NCH (JRANGE / JCH)          // 16 iterations

typedef _Float16 half8 __attribute__((ext_vector_type(8)));
typedef float floatx4 __attribute__((ext_vector_type(4)));
typedef float f32x4 __attribute__((ext_vector_type(4)));

__device__ __align__(16) float g_Wh[N_NODES * F_OUT];                  // 4 MB
__device__ __align__(16) _Float16 g_WhT[(size_t)F_OUT * N_NODES];      // 2 MB
__device__ __align__(16) float g_f1[N_NODES];
__device__ __align__(16) float g_f2[N_NODES];
__device__ __align__(16) float g_part[JSPLIT][N_NODES * F_OUT];        // 16 MB
__device__ __align__(16) float g_spart[JSPLIT][N_NODES];               // 128 KB

#define GLD16NT(lds, gp)                                                      \
  __builtin_amdgcn_global_load_lds(                                           \
      (const __attribute__((address_space(1))) unsigned int*)(gp),            \
      (__attribute__((address_space(3))) unsigned int*)(lds), 16, 0, 2)

// ---------------- Kernel A: Wh = h @ W ----------------
__global__ __launch_bounds__(256, 2) void wh_kernel(
    const float* __restrict__ h, const float* __restrict__ W) {
  __shared__ float hT[F_IN][20];  // pad 20 keeps &hT[k][rg*8] 16B-aligned
  const int t = threadIdx.x;
  const int i0 = blockIdx.x * 16;
  {
    const int row = t >> 4;   // 0..15
    const int fu = t & 15;    // float4 unit
#pragma unroll
    for (int r = 0; r < 4; ++r) {
      const int ku = r * 16 + fu;  // 0..63
      const float4 v = *(const float4*)(h + (size_t)(i0 + row) * F_IN + ku * 4);
      hT[ku * 4 + 0][row] = v.x; hT[ku * 4 + 1][row] = v.y;
      hT[ku * 4 + 2][row] = v.z; hT[ku * 4 + 3][row] = v.w;
    }
  }
  __syncthreads();
  const int c = t & 127;
  const int rg = t >> 7;   // 8 rows per thread
  float acc[8];
#pragma unroll
  for (int r = 0; r < 8; ++r) acc[r] = 0.f;
#pragma unroll 8
  for (int k = 0; k < F_IN; ++k) {
    const float wv = W[k * F_OUT + c];
    const float4 x0 = *(const float4*)(&hT[k][rg * 8]);      // lane-uniform -> broadcast
    const float4 x1 = *(const float4*)(&hT[k][rg * 8 + 4]);
    acc[0] = fmaf(x0.x, wv, acc[0]); acc[1] = fmaf(x0.y, wv, acc[1]);
    acc[2] = fmaf(x0.z, wv, acc[2]); acc[3] = fmaf(x0.w, wv, acc[3]);
    acc[4] = fmaf(x1.x, wv, acc[4]); acc[5] = fmaf(x1.y, wv, acc[5]);
    acc[6] = fmaf(x1.z, wv, acc[6]); acc[7] = fmaf(x1.w, wv, acc[7]);
  }
#pragma unroll
  for (int r = 0; r < 8; ++r)
    g_Wh[(size_t)(i0 + rg * 8 + r) * F_OUT + c] = acc[r];
  union { _Float16 hh[8]; uint4 u4; } pk;
#pragma unroll
  for (int r = 0; r < 8; ++r) pk.hh[r] = (_Float16)acc[r];
  *(uint4*)(g_WhT + (size_t)c * N_NODES + i0 + rg * 8) = pk.u4;
}

// ---------------- Kernel B: f1 = Wh@a1, f2 = Wh@a2 ----------------
__global__ __launch_bounds__(256) void f12_kernel(const float* __restrict__ a) {
  const int t = threadIdx.x;
  const int row = blockIdx.x * 2 + (t >> 7);
  const int c = t & 127;
  const float wh = g_Wh[(size_t)row * F_OUT + c];
  float p1 = wh * a[c];
  float p2 = wh * a[F_OUT + c];
  for (int o = 32; o > 0; o >>= 1) {
    p1 += __shfl_down(p1, o, 64);
    p2 += __shfl_down(p2, o, 64);
  }
  __shared__ float s1[4], s2[4];
  const int w = t >> 6;
  if ((t & 63) == 0) { s1[w] = p1; s2[w] = p2; }
  __syncthreads();
  if ((t & 127) == 0) {
    g_f1[row] = s1[w] + s1[w + 1];
    g_f2[row] = s2[w] + s2[w + 1];
  }
}

// ---------------- Kernel C: fused attention (partials) ----------------
__device__ __forceinline__ float score_p(int a, float f2v, float f1r) {
  float s = f1r + f2v;
  s = fmaxf(s, 0.2f * s);  // leaky_relu, alpha=0.2<1
  float arg = (a > 0) ? fmaf(s, 1.44269504088896f, -16.0f) : -1.0e5f;
  return __builtin_amdgcn_exp2f(arg);  // masked -> 0; 2^-16 scale cancels in num/den
}

__global__ __launch_bounds__(256, 4) void gat_attn_kernel(const int* __restrict__ adj) {
  const int t = threadIdx.x;
  const int wave = t >> 6;
  const int lane = t & 63;
  const int mrow = lane & 15;
  const int quad = lane >> 4;
  const int i0 = blockIdx.x * RPB;
  const int js = blockIdx.y;
  const int jbase = js * JRANGE;

  __shared__ int ldsAdj[2][RPB * JCH];   // 2 x 8 KB, rotation-swizzled rows
  __shared__ float ldsO[RPB][F_OUT];     // 8 KB
  __shared__ float ldsS[4][RPB];         // 256 B

  // runtime C/D layout probe: D1[m][n]=m, D2[m][n]=n (self-correcting scatter)
  int rm[4], cm[4];
  {
    half8 a1f, b1f, a2f, b2f;
#pragma unroll
    for (int e = 0; e < 8; ++e) {
      a1f[e] = (_Float16)0; b1f[e] = (_Float16)0;
      a2f[e] = (_Float16)0; b2f[e] = (_Float16)0;
    }
    if (quad == 0) {
      a1f[0] = (_Float16)mrow; b1f[0] = (_Float16)1;
      a2f[0] = (_Float16)1;    b2f[0] = (_Float16)mrow;
    }
    floatx4 d1 = (floatx4)0.f, d2 = (floatx4)0.f;
    d1 = __builtin_amdgcn_mfma_f32_16x16x32_f16(a1f, b1f, d1, 0, 0, 0);
    d2 = __builtin_amdgcn_mfma_f32_16x16x32_f16(a2f, b2f, d2, 0, 0, 0);
#pragma unroll
    for (int r = 0; r < 4; ++r) { rm[r] = (int)d1[r]; cm[r] = (int)d2[r]; }
  }

  const float f1r = g_f1[i0 + mrow];

  half8 ones;
#pragma unroll
  for (int e = 0; e < 8; ++e) ones[e] = (_Float16)1;

  floatx4 acc[8];
  floatx4 asum = (floatx4)0.f;
#pragma unroll
  for (int ct = 0; ct < 8; ++ct) acc[ct] = (floatx4)0.f;

  // DMA chunk cc into buffer bb. Row m, global 16B-unit u lands at LDS slot
  // ((u+m)&31) of row m (slot = lane&31 in the DMA; 2 rows per instruction).
#define DMA(cc, bb) do {                                                      \
    _Pragma("unroll")                                                         \
    for (int R = 0; R < 2; ++R) {                                             \
      const int m0 = wave * 4 + R * 2;                                        \
      const int m = m0 + (lane >> 5);                                         \
      const int u = ((lane & 31) - m) & 31;                                   \
      const int* gp = adj + (size_t)(i0 + m) * N_NODES + jbase + (cc) * JCH + u * 4; \
      GLD16NT(&ldsAdj[bb][m0 * JCH], gp);                                     \
    }                                                                         \
  } while (0)

  DMA(0, 0);
  __syncthreads();

  const int jloc = wave * 32 + quad * 8;   // wave's j-slice within chunk
  const int u0 = jloc >> 2;                // 16B-unit index within row

#pragma unroll 1
  for (int c = 0; c < NCH; ++c) {
    const int b = c & 1;
    const int jglob = jbase + c * JCH + jloc;

    // B-frags + f2 first (vmcnt FIFO: their waits leave the DMA in flight)
    half8 bfr[8];
#pragma unroll
    for (int ct = 0; ct < 8; ++ct)
      bfr[ct] = *(const half8*)(g_WhT + (size_t)(ct * 16 + mrow) * N_NODES + jglob);
    const float4 F0 = *(const float4*)(g_f2 + jglob);
    const float4 F1 = *(const float4*)(g_f2 + jglob + 4);

    if (c + 1 < NCH) DMA(c + 1, b ^ 1);

    // adj from LDS (swizzled readback; 2-way bank aliasing = free)
    const char* base = (const char*)&ldsAdj[b][0];
    const int4 A0 = *(const int4*)(base + mrow * 512 + (((u0 + mrow) & 31) << 4));
    const int4 A1 = *(const int4*)(base + mrow * 512 + (((u0 + 1 + mrow) & 31) << 4));

    half8 af;
    af[0] = (_Float16)score_p(A0.x, F0.x, f1r);
    af[1] = (_Float16)score_p(A0.y, F0.y, f1r);
    af[2] = (_Float16)score_p(A0.z, F0.z, f1r);
    af[3] = (_Float16)score_p(A0.w, F0.w, f1r);
    af[4] = (_Float16)score_p(A1.x, F1.x, f1r);
    af[5] = (_Float16)score_p(A1.y, F1.y, f1r);
    af[6] = (_Float16)score_p(A1.z, F1.z, f1r);
    af[7] = (_Float16)score_p(A1.w, F1.w, f1r);

#pragma unroll
    for (int ct = 0; ct < 8; ++ct)
      acc[ct] = __builtin_amdgcn_mfma_f32_16x16x32_f16(af, bfr[ct], acc[ct], 0, 0, 0);
    asum = __builtin_amdgcn_mfma_f32_16x16x32_f16(af, ones, asum, 0, 0, 0);

    __syncthreads();  // vmcnt(0)+barrier: DMA(c+1) done, buffer swap safe
  }
#undef DMA

  // psum per row: asum cols all equal; quad q holds rows rm[0..3] (probe-correct)
  if (mrow == 0) {
#pragma unroll
    for (int r = 0; r < 4; ++r) ldsS[wave][rm[r]] = asum[r];
  }
  // serialized wave-add of the 16x128 tile
  for (int w = 0; w < 4; ++w) {
    if (wave == w) {
#pragma unroll
      for (int ct = 0; ct < 8; ++ct)
#pragma unroll
        for (int r = 0; r < 4; ++r) {
          float* p = &ldsO[rm[r]][ct * 16 + cm[r]];
          if (w == 0) *p = acc[ct][r];
          else        *p += acc[ct][r];
        }
    }
    __syncthreads();
  }
  {
    const int row = t >> 4;        // 16 threads per row
    const int c0 = (t & 15) * 8;
    float* dst = g_part[js] + (size_t)(i0 + row) * F_OUT + c0;
    *(f32x4*)(dst + 0) = *(const f32x4*)(&ldsO[row][c0 + 0]);
    *(f32x4*)(dst + 4) = *(const f32x4*)(&ldsO[row][c0 + 4]);
    if (t < RPB)
      g_spart[js][i0 + t] = ldsS[0][t] + ldsS[1][t] + ldsS[2][t] + ldsS[3][t];
  }
}

// ---------------- Kernel D: combine partials + normalize ----------------
__global__ __launch_bounds__(256) void comb_kernel(float* __restrict__ out) {
  const int u = blockIdx.x * 256 + threadIdx.x;  // float4 unit
  const int row = u >> 5;                        // 32 float4 per row
  const float s = g_spart[0][row] + g_spart[1][row] +
                  g_spart[2][row] + g_spart[3][row];
  const f32x4 v = ((const f32x4*)g_part[0])[u] + ((const f32x4*)g_part[1])[u] +
                  ((const f32x4*)g_part[2])[u] + ((const f32x4*)g_part[3])[u];
  ((f32x4*)out)[u] = v * (1.0f / s);
}

extern "C" void kernel_launch(void* const* d_in, const int* in_sizes, int n_in,
                              void* d_out, int out_size, void* d_ws, size_t ws_size,
                              hipStream_t stream) {
  const float* h = (const float*)d_in[0];
  const int* adj = (const int*)d_in[1];
  const float* W = (const float*)d_in[2];
  const float* a = (const float*)d_in[3];
  float* out = (float*)d_out;
  (void)d_ws; (void)ws_size;

  wh_kernel<<<dim3(N_NODES / 16), dim3(256), 0, stream>>>(h, W);
  f12_kernel<<<dim3(N_NODES / 2), dim3(256), 0, stream>>>(a);
  gat_attn_kernel<<<dim3(N_NODES / RPB, JSPLIT), dim3(256), 0, stream>>>(adj);
  comb_kernel<<<dim3(N_NODES * F_OUT / 4 / 256), dim3(256), 0, stream>>>(out);
}

// Round 6
// 466.580 us; speedup vs baseline: 1.0235x; 1.0235x over previous
//
#include <hip/hip_runtime.h>

// GAT layer, N=8192, F_IN=256, F_OUT=128.
// K1 wh: Wh = h@W (fp32 VALU) + WhT (f16 transposed [c][j]).
// K2 f12: f1 = Wh@a1, f2 = Wh@a2.
// K3 attn: ZERO-BARRIER streaming loop. Block = 128 rows x 512-j (JSPLIT=16).
//   Wave owns 32 rows (2 MFMA tiles) x all 512 j -> 16 iters of JCH=32.
//   Per-wave PRIVATE LDS double buffer for adj (4KB/buf), filled by
//   global_load_lds (16B, NT). Per iter: [bfr(8)+f2(2) loads][DMA(c+1) 4]
//   [sched_barrier][s_waitcnt vmcnt(14) == drain DMA(c) only][sched_barrier]
//   [ds_read -> scores -> f16 MFMA]. Compiler's bfr wait = vmcnt(4), leaves
//   DMA(c+1) in flight. No __syncthreads anywhere; waves fully independent.
//   Epilogue: scatter acc into own (dead) adj bufs w/ rotation swizzle,
//   read coalesced, write g_part[js]. psum via ones-MFMA -> g_spart.
// K4 comb: sum 16 partials, normalize.
// NOTE: dur_us includes ~250us harness reset (1GiB ws fill + adj restore).

#define N_NODES 8192
#define F_IN 256
#define F_OUT 128
#define RPB 128                     // rows per block (4 waves x 32)
#define JCH 32                      // j per iteration per wave
#define JSPLIT 16
#define JRANGE (N_NODES / JSPLIT)   // 512
#define NCH (JRANGE / JCH)          // 16 iterations

typedef _Float16 half8 __attribute__((ext_vector_type(8)));
typedef float floatx4 __attribute__((ext_vector_type(4)));
typedef float f32x4 __attribute__((ext_vector_type(4)));

__device__ __align__(16) float g_Wh[N_NODES * F_OUT];                  // 4 MB
__device__ __align__(16) _Float16 g_WhT[(size_t)F_OUT * N_NODES];      // 2 MB
__device__ __align__(16) float g_f1[N_NODES];
__device__ __align__(16) float g_f2[N_NODES];
__device__ __align__(16) float g_part[JSPLIT][N_NODES * F_OUT];        // 64 MB
__device__ __align__(16) float g_spart[JSPLIT][N_NODES];               // 512 KB

#define GLD16NT(lds, gp)                                                      \
  __builtin_amdgcn_global_load_lds(                                           \
      (const __attribute__((address_space(1))) unsigned int*)(gp),            \
      (__attribute__((address_space(3))) unsigned int*)(lds), 16, 0, 2)

// s_waitcnt vmcnt(14): vm low [3:0]=14, exp [6:4]=7, lgkm [11:8]=15
#define WAITVM14() __builtin_amdgcn_s_waitcnt(0x0F7E)

// ---------------- Kernel A: Wh = h @ W ----------------
__global__ __launch_bounds__(256, 2) void wh_kernel(
    const float* __restrict__ h, const float* __restrict__ W) {
  __shared__ float hT[F_IN][20];  // pad 20 keeps &hT[k][rg*8] 16B-aligned
  const int t = threadIdx.x;
  const int i0 = blockIdx.x * 16;
  {
    const int row = t >> 4;   // 0..15
    const int fu = t & 15;    // float4 unit
#pragma unroll
    for (int r = 0; r < 4; ++r) {
      const int ku = r * 16 + fu;  // 0..63
      const float4 v = *(const float4*)(h + (size_t)(i0 + row) * F_IN + ku * 4);
      hT[ku * 4 + 0][row] = v.x; hT[ku * 4 + 1][row] = v.y;
      hT[ku * 4 + 2][row] = v.z; hT[ku * 4 + 3][row] = v.w;
    }
  }
  __syncthreads();
  const int c = t & 127;
  const int rg = t >> 7;   // 8 rows per thread
  float acc[8];
#pragma unroll
  for (int r = 0; r < 8; ++r) acc[r] = 0.f;
#pragma unroll 8
  for (int k = 0; k < F_IN; ++k) {
    const float wv = W[k * F_OUT + c];
    const float4 x0 = *(const float4*)(&hT[k][rg * 8]);
    const float4 x1 = *(const float4*)(&hT[k][rg * 8 + 4]);
    acc[0] = fmaf(x0.x, wv, acc[0]); acc[1] = fmaf(x0.y, wv, acc[1]);
    acc[2] = fmaf(x0.z, wv, acc[2]); acc[3] = fmaf(x0.w, wv, acc[3]);
    acc[4] = fmaf(x1.x, wv, acc[4]); acc[5] = fmaf(x1.y, wv, acc[5]);
    acc[6] = fmaf(x1.z, wv, acc[6]); acc[7] = fmaf(x1.w, wv, acc[7]);
  }
#pragma unroll
  for (int r = 0; r < 8; ++r)
    g_Wh[(size_t)(i0 + rg * 8 + r) * F_OUT + c] = acc[r];
  union { _Float16 hh[8]; uint4 u4; } pk;
#pragma unroll
  for (int r = 0; r < 8; ++r) pk.hh[r] = (_Float16)acc[r];
  *(uint4*)(g_WhT + (size_t)c * N_NODES + i0 + rg * 8) = pk.u4;
}

// ---------------- Kernel B: f1 = Wh@a1, f2 = Wh@a2 ----------------
__global__ __launch_bounds__(256) void f12_kernel(const float* __restrict__ a) {
  const int t = threadIdx.x;
  const int row = blockIdx.x * 2 + (t >> 7);
  const int c = t & 127;
  const float wh = g_Wh[(size_t)row * F_OUT + c];
  float p1 = wh * a[c];
  float p2 = wh * a[F_OUT + c];
  for (int o = 32; o > 0; o >>= 1) {
    p1 += __shfl_down(p1, o, 64);
    p2 += __shfl_down(p2, o, 64);
  }
  __shared__ float s1[4], s2[4];
  const int w = t >> 6;
  if ((t & 63) == 0) { s1[w] = p1; s2[w] = p2; }
  __syncthreads();
  if ((t & 127) == 0) {
    g_f1[row] = s1[w] + s1[w + 1];
    g_f2[row] = s2[w] + s2[w + 1];
  }
}

// ---------------- Kernel C: fused attention (partials) ----------------
__device__ __forceinline__ float score_p(int a, float f2v, float f1r) {
  float s = f1r + f2v;
  s = fmaxf(s, 0.2f * s);  // leaky_relu, alpha=0.2<1
  float arg = (a > 0) ? fmaf(s, 1.44269504088896f, -16.0f) : -1.0e5f;
  return __builtin_amdgcn_exp2f(arg);  // masked -> 0; 2^-16 scale cancels
}

__global__ __launch_bounds__(256, 3) void gat_attn_kernel(const int* __restrict__ adj) {
  const int t = threadIdx.x;
  const int wave = t >> 6;
  const int lane = t & 63;
  const int mrow = lane & 15;
  const int quad = lane >> 4;
  const int i0 = blockIdx.x * RPB;
  const int js = blockIdx.y;
  const int jbase = js * JRANGE;
  const int rowbase = i0 + wave * 32;   // wave's 32 rows (2 MFMA tiles)

  __shared__ int ldsAdj[4][2][1024];    // per-wave private double buffer, 32 KB

  const float f1r0 = g_f1[rowbase + mrow];
  const float f1r1 = g_f1[rowbase + 16 + mrow];

  half8 ones;
#pragma unroll
  for (int e = 0; e < 8; ++e) ones[e] = (_Float16)1;

  floatx4 acc[2][8];
  floatx4 asum[2];
#pragma unroll
  for (int tl = 0; tl < 2; ++tl) {
    asum[tl] = (floatx4)0.f;
#pragma unroll
    for (int ct = 0; ct < 8; ++ct) acc[tl][ct] = (floatx4)0.f;
  }

  // DMA chunk cc -> buf bb. 4 instrs, 8 rows each. Lane l: r=R*8+(l>>3),
  // slot s=l&7 holds global 16B-unit ((s-r)&7)  (rotation swizzle so the
  // lane-contiguous DMA coexists with 2-way-free ds_read_b128 readback).
#define DMA(cc, bb) do {                                                      \
    _Pragma("unroll")                                                         \
    for (int R = 0; R < 4; ++R) {                                             \
      const int rr = R * 8 + (lane >> 3);                                     \
      const int uu = ((lane & 7) - rr) & 7;                                   \
      const int* gp = adj + (size_t)(rowbase + rr) * N_NODES                  \
                      + jbase + (cc) * JCH + uu * 4;                          \
      GLD16NT((char*)&ldsAdj[wave][bb][0] + R * 1024, gp);                    \
    }                                                                         \
  } while (0)

  DMA(0, 0);

#pragma unroll 1
  for (int c = 0; c < NCH; ++c) {
    const int jglob = jbase + c * JCH + quad * 8;

    // bfr + f2 first, DMA(c+1) last: FIFO order [DMA(c)4][bfr8,F2][DMA(c+1)4]
    half8 bfr[8];
#pragma unroll
    for (int ct = 0; ct < 8; ++ct)
      bfr[ct] = *(const half8*)(g_WhT + (size_t)(ct * 16 + mrow) * N_NODES + jglob);
    const float4 F0 = *(const float4*)(g_f2 + jglob);
    const float4 F1 = *(const float4*)(g_f2 + jglob + 4);

    DMA((c + 1) & (NCH - 1), (c + 1) & 1);   // last iter: harmless wrap

    __builtin_amdgcn_sched_barrier(0);
    WAITVM14();   // drains exactly DMA(c); leaves bfr,F,DMA(c+1) in flight
    __builtin_amdgcn_sched_barrier(0);

    // adj from this wave's private buffer (swizzled readback)
    const char* wbuf = (const char*)&ldsAdj[wave][c & 1][0];
    const int s0 = ((quad * 2 + mrow) & 7) * 16;
    const int s1 = ((quad * 2 + 1 + mrow) & 7) * 16;
    const int4 A00 = *(const int4*)(wbuf + mrow * 128 + s0);
    const int4 A01 = *(const int4*)(wbuf + mrow * 128 + s1);
    const int4 A10 = *(const int4*)(wbuf + (16 + mrow) * 128 + s0);
    const int4 A11 = *(const int4*)(wbuf + (16 + mrow) * 128 + s1);

    half8 af0, af1;
    af0[0] = (_Float16)score_p(A00.x, F0.x, f1r0);
    af0[1] = (_Float16)score_p(A00.y, F0.y, f1r0);
    af0[2] = (_Float16)score_p(A00.z, F0.z, f1r0);
    af0[3] = (_Float16)score_p(A00.w, F0.w, f1r0);
    af0[4] = (_Float16)score_p(A01.x, F1.x, f1r0);
    af0[5] = (_Float16)score_p(A01.y, F1.y, f1r0);
    af0[6] = (_Float16)score_p(A01.z, F1.z, f1r0);
    af0[7] = (_Float16)score_p(A01.w, F1.w, f1r0);
    af1[0] = (_Float16)score_p(A10.x, F0.x, f1r1);
    af1[1] = (_Float16)score_p(A10.y, F0.y, f1r1);
    af1[2] = (_Float16)score_p(A10.z, F0.z, f1r1);
    af1[3] = (_Float16)score_p(A10.w, F0.w, f1r1);
    af1[4] = (_Float16)score_p(A11.x, F1.x, f1r1);
    af1[5] = (_Float16)score_p(A11.y, F1.y, f1r1);
    af1[6] = (_Float16)score_p(A11.z, F1.z, f1r1);
    af1[7] = (_Float16)score_p(A11.w, F1.w, f1r1);

#pragma unroll
    for (int ct = 0; ct < 8; ++ct) {
      acc[0][ct] = __builtin_amdgcn_mfma_f32_16x16x32_f16(af0, bfr[ct], acc[0][ct], 0, 0, 0);
      acc[1][ct] = __builtin_amdgcn_mfma_f32_16x16x32_f16(af1, bfr[ct], acc[1][ct], 0, 0, 0);
    }
    asum[0] = __builtin_amdgcn_mfma_f32_16x16x32_f16(af0, ones, asum[0], 0, 0, 0);
    asum[1] = __builtin_amdgcn_mfma_f32_16x16x32_f16(af1, ones, asum[1], 0, 0, 0);
  }
#undef DMA

  // -------- epilogue (wave-private; NO barriers) --------
  __builtin_amdgcn_s_waitcnt(0);  // retire wrapped DMA before reusing bufs
  float* stage = (float*)&ldsAdj[wave][0][0];  // 8 KB, this wave only
  const int orow = lane >> 2;        // 0..15
  const int cb = lane & 3;           // col block of 32

#pragma unroll
  for (int tl = 0; tl < 2; ++tl) {
    // scatter C/D (row=quad*4+r, col=ct*16+mrow; HW-verified by r2-r5 probes)
    // into rotated layout: unit' = (ct*4 + mrow/4 + rowidx) & 31  -> 2-way free
#pragma unroll
    for (int ct = 0; ct < 8; ++ct)
#pragma unroll
      for (int r = 0; r < 4; ++r) {
        const int ri = quad * 4 + r;
        stage[ri * 128 + (((ct * 4) + (mrow >> 2) + ri) & 31) * 4 + (mrow & 3)] =
            acc[tl][ct][r];
      }
    // coalesced-ish readback (un-rotate) + global store
#pragma unroll
    for (int q = 0; q < 8; ++q) {
      const int up = (cb * 8 + q + orow) & 31;
      const f32x4 v = *(const f32x4*)(stage + orow * 128 + up * 4);
      *(f32x4*)(g_part[js] + (size_t)(rowbase + tl * 16 + orow) * F_OUT +
                cb * 32 + q * 4) = v;
    }
    if (mrow == 0) {
#pragma unroll
      for (int r = 0; r < 4; ++r)
        g_spart[js][rowbase + tl * 16 + quad * 4 + r] = asum[tl][r];
    }
  }
}

// ---------------- Kernel D: combine partials + normalize ----------------
__global__ __launch_bounds__(256) void comb_kernel(float* __restrict__ out) {
  const int u = blockIdx.x * 256 + threadIdx.x;  // float4 unit
  const int row = u >> 5;                        // 32 float4 per row
  float s = 0.f;
  f32x4 v = (f32x4)0.f;
#pragma unroll
  for (int p = 0; p < JSPLIT; ++p) {
    s += g_spart[p][row];
    v += ((const f32x4*)g_part[p])[u];
  }
  ((f32x4*)out)[u] = v * (1.0f / s);
}

extern "C" void kernel_launch(void* const* d_in, const int* in_sizes, int n_in,
                              void* d_out, int out_size, void* d_ws, size_t ws_size,
                              hipStream_t stream) {
  const float* h = (const float*)d_in[0];
  const int* adj = (const int*)d_in[1];
  const float* W = (const float*)d_in[2];
  const float* a = (const float*)d_in[3];
  float* out = (float*)d_out;
  (void)d_ws; (void)ws_size;

  wh_kernel<<<dim3(N_NODES / 16), dim3(256), 0, stream>>>(h, W);
  f12_kernel<<<dim3(N_NODES / 2), dim3(256), 0, stream>>>(a);
  gat_attn_kernel<<<dim3(N_NODES / RPB, JSPLIT), dim3(256), 0, stream>>>(adj);
  comb_kernel<<<dim3(N_NODES * F_OUT / 4 / 256), dim3(256), 0, stream>>>(out);
}

// Round 7
// 435.534 us; speedup vs baseline: 1.0965x; 1.0713x over previous
//
#include <hip/hip_runtime.h>

// GAT layer, N=8192, F_IN=256, F_OUT=128.
// K1 wh: Wh = h@W (fp32 VALU) + WhT (f16 transposed [c][j]).
// K2 f12: f1 = Wh@a1, f2 = Wh@a2.
// K3 attn: RPB=64 rows/block, JSPLIT=4 -> 512 blocks (2/CU). 4 waves split the
//   128-j chunk. Hot loop: pure VGPR loads, straight-line, NO LDS, NO barriers.
//   Per iter 18 independent VMEM (bfr x8 shared by 4 row-tiles, f2 x2,
//   adj-NT x8) -> one batched latency per iter instead of r3's 14 serialized
//   (VGPR budget: launch_bounds(256,2) -> ~240 regs, r3 failed at 80).
//   4 tiles x 8 ct MFMA 16x16x32 f16; psum via ones-MFMA. Epilogue-only LDS.
// K4 comb: sum 4 partials, normalize.
// NOTE: dur_us includes ~300us harness reset (1GiB ws fill + 256MB adj
// restore) -- structural floor ~360us.

#define N_NODES 8192
#define F_IN 256
#define F_OUT 128
#define RPB 64                      // rows per block (4 MFMA row-tiles)
#define JCH 128                     // j per chunk (split 4 ways by waves)
#define JSPLIT 4
#define JRANGE (N_NODES / JSPLIT)   // 2048
#define NCH (JRANGE / JCH)          // 16 iterations

typedef _Float16 half8 __attribute__((ext_vector_type(8)));
typedef float floatx4 __attribute__((ext_vector_type(4)));
typedef float f32x4 __attribute__((ext_vector_type(4)));
typedef int i32x4 __attribute__((ext_vector_type(4)));

__device__ __align__(16) float g_Wh[N_NODES * F_OUT];                  // 4 MB
__device__ __align__(16) _Float16 g_WhT[(size_t)F_OUT * N_NODES];      // 2 MB
__device__ __align__(16) float g_f1[N_NODES];
__device__ __align__(16) float g_f2[N_NODES];
__device__ __align__(16) float g_part[JSPLIT][N_NODES * F_OUT];        // 16 MB
__device__ __align__(16) float g_spart[JSPLIT][N_NODES];               // 128 KB

// ---------------- Kernel A: Wh = h @ W ----------------
__global__ __launch_bounds__(256, 2) void wh_kernel(
    const float* __restrict__ h, const float* __restrict__ W) {
  __shared__ float hT[F_IN][20];  // pad 20 keeps &hT[k][rg*8] 16B-aligned
  const int t = threadIdx.x;
  const int i0 = blockIdx.x * 16;
  {
    const int row = t >> 4;   // 0..15
    const int fu = t & 15;    // float4 unit
#pragma unroll
    for (int r = 0; r < 4; ++r) {
      const int ku = r * 16 + fu;  // 0..63
      const float4 v = *(const float4*)(h + (size_t)(i0 + row) * F_IN + ku * 4);
      hT[ku * 4 + 0][row] = v.x; hT[ku * 4 + 1][row] = v.y;
      hT[ku * 4 + 2][row] = v.z; hT[ku * 4 + 3][row] = v.w;
    }
  }
  __syncthreads();
  const int c = t & 127;
  const int rg = t >> 7;   // 8 rows per thread
  float acc[8];
#pragma unroll
  for (int r = 0; r < 8; ++r) acc[r] = 0.f;
#pragma unroll 8
  for (int k = 0; k < F_IN; ++k) {
    const float wv = W[k * F_OUT + c];
    const float4 x0 = *(const float4*)(&hT[k][rg * 8]);
    const float4 x1 = *(const float4*)(&hT[k][rg * 8 + 4]);
    acc[0] = fmaf(x0.x, wv, acc[0]); acc[1] = fmaf(x0.y, wv, acc[1]);
    acc[2] = fmaf(x0.z, wv, acc[2]); acc[3] = fmaf(x0.w, wv, acc[3]);
    acc[4] = fmaf(x1.x, wv, acc[4]); acc[5] = fmaf(x1.y, wv, acc[5]);
    acc[6] = fmaf(x1.z, wv, acc[6]); acc[7] = fmaf(x1.w, wv, acc[7]);
  }
#pragma unroll
  for (int r = 0; r < 8; ++r)
    g_Wh[(size_t)(i0 + rg * 8 + r) * F_OUT + c] = acc[r];
  union { _Float16 hh[8]; uint4 u4; } pk;
#pragma unroll
  for (int r = 0; r < 8; ++r) pk.hh[r] = (_Float16)acc[r];
  *(uint4*)(g_WhT + (size_t)c * N_NODES + i0 + rg * 8) = pk.u4;
}

// ---------------- Kernel B: f1 = Wh@a1, f2 = Wh@a2 ----------------
__global__ __launch_bounds__(256) void f12_kernel(const float* __restrict__ a) {
  const int t = threadIdx.x;
  const int row = blockIdx.x * 2 + (t >> 7);
  const int c = t & 127;
  const float wh = g_Wh[(size_t)row * F_OUT + c];
  float p1 = wh * a[c];
  float p2 = wh * a[F_OUT + c];
  for (int o = 32; o > 0; o >>= 1) {
    p1 += __shfl_down(p1, o, 64);
    p2 += __shfl_down(p2, o, 64);
  }
  __shared__ float s1[4], s2[4];
  const int w = t >> 6;
  if ((t & 63) == 0) { s1[w] = p1; s2[w] = p2; }
  __syncthreads();
  if ((t & 127) == 0) {
    g_f1[row] = s1[w] + s1[w + 1];
    g_f2[row] = s2[w] + s2[w + 1];
  }
}

// ---------------- Kernel C: fused attention (partials) ----------------
__device__ __forceinline__ float score_p(int a, float f2v, float f1r) {
  float s = f1r + f2v;
  s = fmaxf(s, 0.2f * s);  // leaky_relu, alpha=0.2<1
  float arg = (a > 0) ? fmaf(s, 1.44269504088896f, -16.0f) : -1.0e5f;
  return __builtin_amdgcn_exp2f(arg);  // masked -> 0; 2^-16 scale cancels
}

__global__ __launch_bounds__(256, 2) void gat_attn_kernel(const int* __restrict__ adj) {
  const int t = threadIdx.x;
  const int wave = t >> 6;
  const int lane = t & 63;
  const int mrow = lane & 15;
  const int quad = lane >> 4;
  const int i0 = blockIdx.x * RPB;
  const int js = blockIdx.y;
  const int jbase = js * JRANGE;
  const int jloc = wave * 32 + quad * 8;   // wave's j-slice within chunk

  float f1r[4];
#pragma unroll
  for (int tl = 0; tl < 4; ++tl) f1r[tl] = g_f1[i0 + tl * 16 + mrow];

  half8 ones;
#pragma unroll
  for (int e = 0; e < 8; ++e) ones[e] = (_Float16)1;

  floatx4 acc[4][8];   // 128 VGPRs
  floatx4 asum[4];
#pragma unroll
  for (int tl = 0; tl < 4; ++tl) {
    asum[tl] = (floatx4)0.f;
#pragma unroll
    for (int ct = 0; ct < 8; ++ct) acc[tl][ct] = (floatx4)0.f;
  }

#pragma unroll 1
  for (int c = 0; c < NCH; ++c) {
    const int jglob = jbase + c * JCH + jloc;

    // ---- all 18 loads, mutually independent: one batched drain per iter ----
    half8 bfr[8];
#pragma unroll
    for (int ct = 0; ct < 8; ++ct)
      bfr[ct] = *(const half8*)(g_WhT + (size_t)(ct * 16 + mrow) * N_NODES + jglob);
    const float4 F0 = *(const float4*)(g_f2 + jglob);
    const float4 F1 = *(const float4*)(g_f2 + jglob + 4);
    i32x4 A0[4], A1[4];
#pragma unroll
    for (int tl = 0; tl < 4; ++tl) {
      const int* ap = adj + (size_t)(i0 + tl * 16 + mrow) * N_NODES + jglob;
      A0[tl] = __builtin_nontemporal_load((const i32x4*)ap);
      A1[tl] = __builtin_nontemporal_load((const i32x4*)ap + 1);
    }

    // ---- compute: 4 tiles x (8 scores -> 9 MFMA) ----
#pragma unroll
    for (int tl = 0; tl < 4; ++tl) {
      half8 af;
      af[0] = (_Float16)score_p(A0[tl][0], F0.x, f1r[tl]);
      af[1] = (_Float16)score_p(A0[tl][1], F0.y, f1r[tl]);
      af[2] = (_Float16)score_p(A0[tl][2], F0.z, f1r[tl]);
      af[3] = (_Float16)score_p(A0[tl][3], F0.w, f1r[tl]);
      af[4] = (_Float16)score_p(A1[tl][0], F1.x, f1r[tl]);
      af[5] = (_Float16)score_p(A1[tl][1], F1.y, f1r[tl]);
      af[6] = (_Float16)score_p(A1[tl][2], F1.z, f1r[tl]);
      af[7] = (_Float16)score_p(A1[tl][3], F1.w, f1r[tl]);
#pragma unroll
      for (int ct = 0; ct < 8; ++ct)
        acc[tl][ct] = __builtin_amdgcn_mfma_f32_16x16x32_f16(af, bfr[ct], acc[tl][ct], 0, 0, 0);
      asum[tl] = __builtin_amdgcn_mfma_f32_16x16x32_f16(af, ones, asum[tl], 0, 0, 0);
    }
  }

  // -------- epilogue: cross-wave j-reduction via LDS (barriers OK here) -----
  __shared__ float ldsO[RPB][F_OUT];   // 32 KB
  __shared__ float ldsS[4][RPB];       // 1 KB

  if (mrow == 0) {
#pragma unroll
    for (int tl = 0; tl < 4; ++tl)
#pragma unroll
      for (int r = 0; r < 4; ++r)
        ldsS[wave][tl * 16 + quad * 4 + r] = asum[tl][r];
  }
  for (int w = 0; w < 4; ++w) {
    if (wave == w) {
#pragma unroll
      for (int tl = 0; tl < 4; ++tl)
#pragma unroll
        for (int ct = 0; ct < 8; ++ct)
#pragma unroll
          for (int r = 0; r < 4; ++r) {
            // C/D: row = quad*4+r, col = ct*16+mrow (HW-verified r2-r5 probes)
            float* p = &ldsO[tl * 16 + quad * 4 + r][ct * 16 + mrow];
            if (w == 0) *p = acc[tl][ct][r];
            else        *p += acc[tl][ct][r];
          }
    }
    __syncthreads();
  }
  {
    const int row = t >> 2;          // 0..63
    const int c0 = (t & 3) * 32;     // 4 segs of 32 cols
    float* dst = g_part[js] + (size_t)(i0 + row) * F_OUT + c0;
#pragma unroll
    for (int q = 0; q < 8; ++q)
      *(f32x4*)(dst + q * 4) = *(const f32x4*)(&ldsO[row][c0 + q * 4]);
    if ((t & 3) == 0)
      g_spart[js][i0 + row] = ldsS[0][row] + ldsS[1][row] +
                              ldsS[2][row] + ldsS[3][row];
  }
}

// ---------------- Kernel D: combine partials + normalize ----------------
__global__ __launch_bounds__(256) void comb_kernel(float* __restrict__ out) {
  const int u = blockIdx.x * 256 + threadIdx.x;  // float4 unit
  const int row = u >> 5;                        // 32 float4 per row
  float s = 0.f;
  f32x4 v = (f32x4)0.f;
#pragma unroll
  for (int p = 0; p < JSPLIT; ++p) {
    s += g_spart[p][row];
    v += ((const f32x4*)g_part[p])[u];
  }
  ((f32x4*)out)[u] = v * (1.0f / s);
}

extern "C" void kernel_launch(void* const* d_in, const int* in_sizes, int n_in,
                              void* d_out, int out_size, void* d_ws, size_t ws_size,
                              hipStream_t stream) {
  const float* h = (const float*)d_in[0];
  const int* adj = (const int*)d_in[1];
  const float* W = (const float*)d_in[2];
  const float* a = (const float*)d_in[3];
  float* out = (float*)d_out;
  (void)d_ws; (void)ws_size;

  wh_kernel<<<dim3(N_NODES / 16), dim3(256), 0, stream>>>(h, W);
  f12_kernel<<<dim3(N_NODES / 2), dim3(256), 0, stream>>>(a);
  gat_attn_kernel<<<dim3(N_NODES / RPB, JSPLIT), dim3(256), 0, stream>>>(adj);
  comb_kernel<<<dim3(N_NODES * F_OUT / 4 / 256), dim3(256), 0, stream>>>(out);
}